// Round 11
// baseline (173.568 us; speedup 1.0000x reference)
//
#include <hip/hip_runtime.h>
#include <hip/hip_bf16.h>

#define B_   8
#define SQ_  2048
#define SK_  2048
#define DK_  256
#define DV_  256

#define KT    32                  // keys per staged tile
#define PSTR  40                  // sP row stride (bf16): 32 cols + 8 pad
#define TELEM (KT * DK_)          // 8192 bf16 elems per tile (16 KB)
#define NQB   16                  // 128-row q-blocks per batch
#define NENT  544                 // total (qb,tile) entries per batch
#define NBLK  64                  // chunks per batch (8-9 entries each)

typedef __bf16 bf16x8 __attribute__((ext_vector_type(8)));
typedef __bf16 bf16x4 __attribute__((ext_vector_type(4)));
typedef float  f32x4  __attribute__((ext_vector_type(4)));

// entry list: qb DESCENDING (15..0), tiles ascending within qb.
// cum(q) = first entry index of qb q; nt(q) = 4(q+1) tiles.
__host__ __device__ __forceinline__ int cumf(int q)   { return 544 - 2*(q+1)*(q+2); }
__host__ __device__ __forceinline__ int yfirst(int c) { return (2*c + 1) / 17; }  // block holding entry c

// async global->LDS, 16B per lane; LDS dest is wave-uniform base + lane*16
__device__ __forceinline__ void gl_lds16(const void* g, void* l) {
    __builtin_amdgcn_global_load_lds(
        (const __attribute__((address_space(1))) void*)g,
        (__attribute__((address_space(3))) void*)l, 16, 0, 0);
}

__device__ __forceinline__ int qb_of(int e) {
    int q = 15;
    while (q > 0 && e >= cumf(q) + 4 * (q + 1)) --q;
    return q;
}

// partial-slot base for qb q (skip qbs fully contained in one block: count==1)
__host__ __device__ __forceinline__ int slot_base(int q) {
    int base = 0;
    for (int p = 15; p > q; --p) {
        int c0 = cumf(p), c1 = c0 + 4 * (p + 1) - 1;
        int cnt = yfirst(c1) - yfirst(c0) + 1;
        if (cnt > 1) base += cnt;
    }
    return base;
}

// ---------- kernel 1: K,V -> tile-blocked bf16 (UNCHANGED, proven) ----------
__global__ __launch_bounds__(256)
void make_tiles(const float* __restrict__ K, const float* __restrict__ V,
                __bf16* __restrict__ Kt, __bf16* __restrict__ Vt)
{
    const int b = blockIdx.x, t = blockIdx.y;
    const float* ksrc = K + ((size_t)(b * SK_ + t * KT)) * DK_;
    const float* vsrc = V + ((size_t)(b * SK_ + t * KT)) * DV_;

    float4 kf[8];
    #pragma unroll
    for (int it = 0; it < 4; ++it) {
        int ci  = it * 256 + threadIdx.x;
        int dk8 = ci >> 5;
        int key = ci & 31;
        const float* p = ksrc + (size_t)key * DK_ + dk8 * 8;
        kf[it * 2]     = *(const float4*)(p);
        kf[it * 2 + 1] = *(const float4*)(p + 4);
    }
    const int kc8 = threadIdx.x >> 6;
    const int dv4 = threadIdx.x & 63;
    float4 vf[8];
    {
        const float* p = vsrc + (size_t)(kc8 * 8) * DV_ + dv4 * 4;
        #pragma unroll
        for (int j = 0; j < 8; ++j)
            vf[j] = *(const float4*)(p + (size_t)j * DV_);
    }

    __bf16* kout = Kt + ((size_t)(b * 64 + t)) * TELEM;
    #pragma unroll
    for (int it = 0; it < 4; ++it) {
        int ci = it * 256 + threadIdx.x;
        bf16x8 o;
        o[0] = (__bf16)kf[it*2].x;   o[1] = (__bf16)kf[it*2].y;
        o[2] = (__bf16)kf[it*2].z;   o[3] = (__bf16)kf[it*2].w;
        o[4] = (__bf16)kf[it*2+1].x; o[5] = (__bf16)kf[it*2+1].y;
        o[6] = (__bf16)kf[it*2+1].z; o[7] = (__bf16)kf[it*2+1].w;
        *(bf16x8*)(kout + (size_t)ci * 8) = o;
    }
    __bf16* vout = Vt + ((size_t)(b * 64 + t)) * TELEM;
    {
        bf16x8 o0, o1, o2, o3;
        #pragma unroll
        for (int j = 0; j < 8; ++j) {
            o0[j] = (__bf16)vf[j].x; o1[j] = (__bf16)vf[j].y;
            o2[j] = (__bf16)vf[j].z; o3[j] = (__bf16)vf[j].w;
        }
        __bf16* q = vout + (size_t)(kc8 * 256 + dv4 * 4) * 8;
        *(bf16x8*)(q)      = o0;
        *(bf16x8*)(q + 8)  = o1;
        *(bf16x8*)(q + 16) = o2;
        *(bf16x8*)(q + 24) = o3;
    }
}

// ---------- kernel 2: attention, 128 q-rows x 4 waves x 32 rows (R10 core) ----------
// UNIFORM decomposition: per batch, 544 (qb,tile) entries cut into 64 chunks of
// 8-9 -> 512 blocks, 2/CU, every CU exactly 17 tile-steps (kills the 38% tail
// that capped R10 occupancy at 15%). Chunks cross qb boundaries: flush partials
// (or direct-write when the whole qb is inside), reload qfrag, zero acc; the
// dbuf staging cadence runs uninterrupted across boundaries (entry-based).
// Compute core verbatim R10 (swapped QK^T -> S^T, b64 sP stores, dead-skip).
// mode 1 fallback (tiny ws): one block per qb (grid B x 16), all direct-write.
__global__ __launch_bounds__(256, 2)
void attn_fwd(const float* __restrict__ Qg, const __bf16* __restrict__ Kt,
              const __bf16* __restrict__ Vt, const void* __restrict__ Mv,
              __bf16* __restrict__ Opart, float* __restrict__ Lpart,
              float* __restrict__ Og, int mode, int slots_pb)
{
    __shared__ __align__(16) __bf16 sK[2][TELEM];       // 32 KB
    __shared__ __align__(16) __bf16 sV[2][TELEM];       // 32 KB
    __shared__ __align__(16) __bf16 sP[4][32 * PSTR];   // per-wave 32x32 P, 10 KB

    const int tid  = threadIdx.x;
    const int wv   = tid >> 6;                 // 0..3
    const int lane = tid & 63;
    const int quad = lane >> 4;
    const int l16  = lane & 15;

    const int b = blockIdx.x;                  // fastest -> XCD = b (L2 batch affinity)
    const int y = blockIdx.y;

    int e0, e1;
    if (mode == 0) { e0 = (17 * y) >> 1; e1 = (17 * (y + 1)) >> 1; }
    else           { e0 = cumf(y);       e1 = cumf(y) + 4 * (y + 1); }

    // ---- mask dtype sniff (uniform): int32 0/1 -> <=32 nonzero bytes in first 128 ----
    const unsigned char* Mb = (const unsigned char*)Mv;
    const int*           Mi = (const int*)Mv;
    int nzb = 0;
    {
        const unsigned int* mw = (const unsigned int*)Mv;
        #pragma unroll
        for (int i = 0; i < 32; ++i) {
            unsigned int w = mw[i];
            nzb += ((w & 0x000000ffu) != 0) + ((w & 0x0000ff00u) != 0)
                 + ((w & 0x00ff0000u) != 0) + ((w & 0xff000000u) != 0);
        }
    }
    const bool mask_byte = (nzb > 40);
    const size_t mbase = (size_t)b * SK_;

    const __bf16* Kbase = Kt + (size_t)b * 64 * TELEM;
    const __bf16* Vbase = Vt + (size_t)b * 64 * TELEM;

    bf16x8 qfrag[2][8];
    f32x4  oacc[2][16];
    float  lsum[2];
    int qcur = -1, seg_s = e0, qrow = 0;

    // flush current segment [es, ee) of qb q: direct-write if full coverage
    auto flush_seg = [&](int q, int es, int ee) {
        float l0 = lsum[0], l1 = lsum[1];
        l0 += __shfl_xor(l0, 16); l0 += __shfl_xor(l0, 32);
        l1 += __shfl_xor(l1, 16); l1 += __shfl_xor(l1, 32);
        const int nt = 4 * (q + 1);
        const bool full = (es == cumf(q)) && (ee == cumf(q) + nt);
        if (full) {
            float* op = Og + ((size_t)(b * SQ_ + q * 128 + wv * 32)) * DV_;
            #pragma unroll
            for (int rs = 0; rs < 2; ++rs)
                #pragma unroll
                for (int i = 0; i < 4; ++i) {
                    float ls  = __shfl(rs == 0 ? l0 : l1, quad * 4 + i);
                    float inv = 1.0f / (ls + 1e-7f);
                    #pragma unroll
                    for (int vf = 0; vf < 16; ++vf)
                        op[(size_t)(rs * 16 + quad * 4 + i) * DV_ + vf * 16 + l16]
                            = oacc[rs][vf][i] * inv;
                }
        } else {
            const int slot_loc = slot_base(q) + (y - yfirst(cumf(q)));
            const size_t slot = (size_t)b * slots_pb + slot_loc;
            if (quad == 0) {
                Lpart[slot * 128 + wv * 32 + l16]      = l0;
                Lpart[slot * 128 + wv * 32 + 16 + l16] = l1;
            }
            __bf16* ob = Opart + slot * (size_t)(128 * 256);
            #pragma unroll
            for (int rs = 0; rs < 2; ++rs)
                #pragma unroll
                for (int vf = 0; vf < 16; ++vf)
                    #pragma unroll
                    for (int i = 0; i < 4; ++i)
                        ob[(wv * 32 + rs * 16 + quad * 4 + i) * 256 + vf * 16 + l16]
                            = (__bf16)oacc[rs][vf][i];
        }
    };

    // ---- prologue: stage entry e0's tile into buffer 0 ----
    {
        int te = e0 - cumf(qb_of(e0));
        const __bf16* kg = Kbase + (size_t)te * TELEM;
        const __bf16* vg = Vbase + (size_t)te * TELEM;
        #pragma unroll
        for (int r = 0; r < 4; ++r) {
            int ci = r * 256 + tid;
            gl_lds16(kg + (size_t)ci * 8, (char*)&sK[0][0] + ci * 16);
            gl_lds16(vg + (size_t)ci * 8, (char*)&sV[0][0] + ci * 16);
        }
    }
    __syncthreads();                            // drains vmcnt -> first tile visible

    int cur = 0;
    for (int e = e0; e < e1; ++e) {
        const int q = qb_of(e);
        if (q != qcur) {
            if (qcur >= 0) flush_seg(qcur, seg_s, e);
            qcur = q; seg_s = e;
            qrow = q * 128 + wv * 32;
            // ---- qfrag[rs][kt][j] = Q[qrow+rs*16+l16][kt*32 + quad*8 + j] ----
            #pragma unroll
            for (int rs = 0; rs < 2; ++rs) {
                const float* qp = Qg + ((size_t)(b * SQ_ + qrow + rs * 16 + l16)) * DK_ + quad * 8;
                #pragma unroll
                for (int kt = 0; kt < 8; ++kt) {
                    float4 f0 = *(const float4*)(qp + kt * 32);
                    float4 f1 = *(const float4*)(qp + kt * 32 + 4);
                    bf16x8 qv;
                    qv[0] = (__bf16)f0.x; qv[1] = (__bf16)f0.y; qv[2] = (__bf16)f0.z; qv[3] = (__bf16)f0.w;
                    qv[4] = (__bf16)f1.x; qv[5] = (__bf16)f1.y; qv[6] = (__bf16)f1.z; qv[7] = (__bf16)f1.w;
                    qfrag[rs][kt] = qv;
                }
            }
            #pragma unroll
            for (int rs = 0; rs < 2; ++rs)
                #pragma unroll
                for (int v = 0; v < 16; ++v) oacc[rs][v] = (f32x4){0.f, 0.f, 0.f, 0.f};
            lsum[0] = 0.f; lsum[1] = 0.f;
        }
        const int t  = e - cumf(q);
        const int k0 = t * KT;

        // ---- stage NEXT entry's tile into cur^1 (in flight across compute) ----
        if (e + 1 < e1) {
            int tn = (e + 1) - cumf(qb_of(e + 1));
            const __bf16* kg = Kbase + (size_t)tn * TELEM;
            const __bf16* vg = Vbase + (size_t)tn * TELEM;
            #pragma unroll
            for (int r = 0; r < 4; ++r) {
                int ci = r * 256 + tid;
                gl_lds16(kg + (size_t)ci * 8, (char*)&sK[cur ^ 1][0] + ci * 16);
                gl_lds16(vg + (size_t)ci * 8, (char*)&sV[cur ^ 1][0] + ci * 16);
            }
        }

        // ---- dead-tile skip (wave-uniform): all 32 keys above all 32 rows ----
        if (k0 <= qrow + 31) {
            // ---- S^T = K Q^T: swapped operands (R10-proven) ----
            f32x4 s00 = {0.f,0.f,0.f,0.f}, s01 = {0.f,0.f,0.f,0.f};
            f32x4 s10 = {0.f,0.f,0.f,0.f}, s11 = {0.f,0.f,0.f,0.f};
            __builtin_amdgcn_s_setprio(1);
            #pragma unroll
            for (int kt = 0; kt < 8; ++kt) {
                bf16x8 b0 = *(const bf16x8*)&sK[cur][(size_t)((kt * 4 + quad) * 32 + l16)      * 8];
                bf16x8 b1 = *(const bf16x8*)&sK[cur][(size_t)((kt * 4 + quad) * 32 + 16 + l16) * 8];
                s00 = __builtin_amdgcn_mfma_f32_16x16x32_bf16(b0, qfrag[0][kt], s00, 0, 0, 0);
                s10 = __builtin_amdgcn_mfma_f32_16x16x32_bf16(b1, qfrag[0][kt], s10, 0, 0, 0);
                s01 = __builtin_amdgcn_mfma_f32_16x16x32_bf16(b0, qfrag[1][kt], s01, 0, 0, 0);
                s11 = __builtin_amdgcn_mfma_f32_16x16x32_bf16(b1, qfrag[1][kt], s11, 0, 0, 0);
            }
            __builtin_amdgcn_s_setprio(0);

            // ---- P = exp(S/16) * causal * mask; 4 consecutive keys per lane ----
            #pragma unroll
            for (int kh = 0; kh < 2; ++kh) {
                const int kbase = k0 + kh * 16 + quad * 4;
                float mk[4];
                if (mask_byte) {
                    uchar4 m4 = *(const uchar4*)(Mb + mbase + kbase);
                    mk[0] = m4.x ? 1.f : 0.f; mk[1] = m4.y ? 1.f : 0.f;
                    mk[2] = m4.z ? 1.f : 0.f; mk[3] = m4.w ? 1.f : 0.f;
                } else {
                    int4 m4 = *(const int4*)(Mi + mbase + kbase);
                    mk[0] = m4.x ? 1.f : 0.f; mk[1] = m4.y ? 1.f : 0.f;
                    mk[2] = m4.z ? 1.f : 0.f; mk[3] = m4.w ? 1.f : 0.f;
                }
                #pragma unroll
                for (int rs = 0; rs < 2; ++rs) {
                    f32x4 sv = (rs == 0) ? ((kh == 0) ? s00 : s10)
                                         : ((kh == 0) ? s01 : s11);
                    const int qr = qrow + rs * 16 + l16;
                    bf16x4 pv4;
                    #pragma unroll
                    for (int i = 0; i < 4; ++i) {
                        float p = __expf(sv[i] * 0.0625f);
                        p = (kbase + i <= qr) ? (p * mk[i]) : 0.0f;
                        lsum[rs] += p;
                        pv4[i] = (__bf16)p;
                    }
                    *(bf16x4*)&sP[wv][(rs * 16 + l16) * PSTR + kh * 16 + quad * 4] = pv4;
                }
            }
            asm volatile("s_waitcnt lgkmcnt(0)" ::: "memory");
            __builtin_amdgcn_wave_barrier();

            // ---- O += P V ----
            {
                bf16x8 pa0 = *(const bf16x8*)&sP[wv][(l16)      * PSTR + quad * 8];
                bf16x8 pa1 = *(const bf16x8*)&sP[wv][(16 + l16) * PSTR + quad * 8];
                __builtin_amdgcn_s_setprio(1);
                #pragma unroll
                for (int vf = 0; vf < 16; ++vf) {
                    bf16x8 bv = *(const bf16x8*)&sV[cur][(size_t)(quad * 256 + vf * 16 + l16) * 8];
                    oacc[0][vf] = __builtin_amdgcn_mfma_f32_16x16x32_bf16(pa0, bv, oacc[0][vf], 0, 0, 0);
                    oacc[1][vf] = __builtin_amdgcn_mfma_f32_16x16x32_bf16(pa1, bv, oacc[1][vf], 0, 0, 0);
                }
                __builtin_amdgcn_s_setprio(0);
            }
        }

        __syncthreads();                        // next tile staged + buf[cur] free
        cur ^= 1;
    }
    flush_seg(qcur, seg_s, e1);
}

// ---------- kernel 3: reduce partial slots + normalize ----------
// Grid (B, 64): y = (qb64 0..31, col-half); 64 rows x 128 cols per block.
// qbs fully inside one attn block (count==1) were direct-written -> return.
__global__ __launch_bounds__(512)
void attn_reduce(const __bf16* __restrict__ Opart, const float* __restrict__ Lpart,
                 float* __restrict__ Og, int slots_pb)
{
    const int b    = blockIdx.x;
    const int yy   = blockIdx.y;               // [0, 64)
    const int qb64 = yy >> 1;                  // 64-row block [0, 32)
    const int half = yy & 1;                   // 128-col half
    const int qb   = qb64 >> 1;                // 128-row q-block [0, 16)
    const int rowbase = (qb64 & 1) * 64;

    const int c0 = cumf(qb), c1 = c0 + 4 * (qb + 1) - 1;
    const int chunks = yfirst(c1) - yfirst(c0) + 1;
    if (chunks < 2) return;                    // direct-written by attn_fwd

    const int base = slot_base(qb);
    const int tid  = threadIdx.x;
    const int row  = tid >> 3;                 // 0..63
    const int cg   = tid & 7;                  // 16-col group

    const size_t sbase = (size_t)b * slots_pb + base;
    float acc[16];
    #pragma unroll
    for (int i = 0; i < 16; ++i) acc[i] = 0.f;
    float ls = 0.f;

    for (int s = 0; s < chunks; ++s) {
        const __bf16* p = Opart + (sbase + s) * (size_t)(128 * 256)
                        + (size_t)(rowbase + row) * 256 + half * 128 + cg * 16;
        bf16x8 x0 = *(const bf16x8*)(p);
        bf16x8 x1 = *(const bf16x8*)(p + 8);
        #pragma unroll
        for (int e = 0; e < 8; ++e) { acc[e] += (float)x0[e]; acc[8 + e] += (float)x1[e]; }
        ls += Lpart[(sbase + s) * 128 + rowbase + row];
    }
    const float inv = 1.0f / (ls + 1e-7f);
    float* op = Og + ((size_t)b * SQ_ + qb * 128 + rowbase + row) * DV_ + half * 128 + cg * 16;
    #pragma unroll
    for (int v = 0; v < 4; ++v) {
        float4 o;
        o.x = acc[v * 4 + 0] * inv; o.y = acc[v * 4 + 1] * inv;
        o.z = acc[v * 4 + 2] * inv; o.w = acc[v * 4 + 3] * inv;
        *(float4*)(op + v * 4) = o;
    }
}

extern "C" void kernel_launch(void* const* d_in, const int* in_sizes, int n_in,
                              void* d_out, int out_size, void* d_ws, size_t ws_size,
                              hipStream_t stream) {
    const float* Q = (const float*)d_in[0];
    const float* K = (const float*)d_in[1];
    const float* V = (const float*)d_in[2];
    const void*  M = d_in[3];
    float* Out = (float*)d_out;

    __bf16* Ktl = (__bf16*)d_ws;                          // 8 MB
    __bf16* Vtl = Ktl + (size_t)B_ * 64 * TELEM;          // 8 MB
    __bf16* Opart = Vtl + (size_t)B_ * 64 * TELEM;

    // slot accounting (mirrors device formulas): 76 partial slots per batch
    int slots_pb = 0;
    for (int q = 15; q >= 0; --q) {
        int c0 = cumf(q), c1 = c0 + 4 * (q + 1) - 1;
        int cnt = yfirst(c1) - yfirst(c0) + 1;
        if (cnt > 1) slots_pb += cnt;
    }
    size_t need = (size_t)(16 * 1024 * 1024)
                + (size_t)B_ * slots_pb * (128 * 256) * 2   // Opart bf16 (~40 MB)
                + (size_t)B_ * slots_pb * 128 * 4;          // Lpart f32
    int mode = (ws_size >= need) ? 0 : 1;

    float* Lpart = (float*)(Opart + (size_t)B_ * slots_pb * (128 * 256));

    make_tiles<<<dim3(B_, 64), dim3(256), 0, stream>>>(K, V, Ktl, Vtl);
    if (mode == 0) {
        attn_fwd<<<dim3(B_, NBLK), dim3(256), 0, stream>>>(Q, Ktl, Vtl, M, Opart, Lpart,
                                                           Out, 0, slots_pb);
        attn_reduce<<<dim3(B_, 64), dim3(512), 0, stream>>>(Opart, Lpart, Out, slots_pb);
    } else {
        // degenerate fallback: one block per qb, all direct-write, no partials
        attn_fwd<<<dim3(B_, NQB), dim3(256), 0, stream>>>(Q, Ktl, Vtl, M, Opart, Lpart,
                                                          Out, 1, 0);
    }
}